// Round 21
// baseline (133.716 us; speedup 1.0000x reference)
//
#include <hip/hip_runtime.h>
#include <hip/hip_fp16.h>
#include <math.h>

#define N_NODES 65536
#define B_GRAPHS 64
#define NPG 1024
#define EPG 16384
#define E_TOTAL (B_GRAPHS * EPG)
#define NEG 0.2f

typedef float f32x4 __attribute__((ext_vector_type(4)));
typedef _Float16 f16x8 __attribute__((ext_vector_type(8)));
typedef _Float16 h2v __attribute__((ext_vector_type(2)));
typedef int i32x4 __attribute__((ext_vector_type(4)));
typedef unsigned int uint32;
typedef unsigned short u16;

union FragH { i32x4 i; f16x8 h; uint32 u[4]; };
union H2U { uint32 u; h2v h; };

// raw v_exp_f32 (2^x) — logits bounded by construction [validated R8+]
__device__ __forceinline__ float fast_exp2(float x) {
    float r;
    asm("v_exp_f32 %0, %1" : "=v"(r) : "v"(x));
    return r;
}

__device__ __forceinline__ uint32 f2h2(float a, float b) {
    __half2 h = __float22half2_rn(make_float2(a, b));
    return *(uint32*)&h;
}
__device__ __forceinline__ float2 h2f(uint32 u) {
    __half2 h = *(__half2*)&u;
    return __half22float2(h);
}

// packed f16 accumulate: acc = fv * pe2 + acc   (v_pk_fma_f16) [validated R20]
__device__ __forceinline__ void pk_fma_acc(uint32& acc, uint32 fv, uint32 pe2) {
    asm("v_pk_fma_f16 %0, %1, %2, %0" : "+v"(acc) : "v"(fv), "v"(pe2));
}

// e = fv + fd; e = max(e, NEG*e); sp += dot2(e, av)   (f32 accumulate) [validated R8+]
__device__ __forceinline__ float dot_term(uint32 fvu, h2v fdv, h2v neg2, h2v av, float accum) {
    H2U fv; fv.u = fvu;
    h2v e = fv.h + fdv;                  // v_pk_add_f16
    h2v en = e * neg2;                   // v_pk_mul_f16
    h2v em;
    asm("v_pk_max_f16 %0, %1, %2" : "=v"(em) : "v"(e), "v"(en));
    float sp;
    asm("v_dot2_f32_f16 %0, %1, %2, %3" : "=v"(sp) : "v"(em), "v"(av), "v"(accum));
    return sp;
}

// ---------------- prep: CSR count-sort + degree-sorted descriptors + W frag conv ----------------
__global__ __launch_bounds__(1024) void k_prep(const int* __restrict__ src, const int* __restrict__ dst,
                                               int* __restrict__ rowptr, int* __restrict__ colb,
                                               int2* __restrict__ ndpack,
                                               const float* __restrict__ Ws1, const float* __restrict__ Wd1,
                                               const float* __restrict__ Ws2, const float* __restrict__ Wd2,
                                               __half* __restrict__ Wf1, __half* __restrict__ Wf2) {
    __shared__ int cnt[NPG];
    __shared__ int cur[NPG];
    __shared__ int scol[EPG];   // 64KB
    __shared__ int wsum[16];
    __shared__ int hd[64];
    __shared__ int hcur[64];
    if (blockIdx.x >= B_GRAPHS) {
        int id = (blockIdx.x - B_GRAPHS) * 1024 + threadIdx.x;
        if (id < 32768) {
            int j = id & 7, l = (id >> 3) & 63, c = (id >> 9) & 3, T = id >> 11;
            int k = c * 32 + (l >> 4) * 8 + j;
            int n = (T & 7) * 16 + (l & 15);
            const float* W = (T < 8) ? Ws1 : Wd1;
            Wf1[id] = __float2half_rn(W[k * 128 + n]);
        } else if (id < 40960) {
            int rem = id - 32768;
            int j = rem & 7, l = (rem >> 3) & 63, T = rem >> 9;
            int k = (l >> 4) * 8 + j;
            int n = (T & 7) * 16 + (l & 15);
            const float* W = (T < 8) ? Ws2 : Wd2;
            Wf2[rem] = __float2half_rn(W[k * 128 + n]);
        }
        return;
    }
    int g = blockIdx.x, tid = threadIdx.x;
    int lane = tid & 63, wid = tid >> 6;
    int ebase = g * EPG;
    cnt[tid] = 0;
    __syncthreads();
    for (int e = tid; e < EPG; e += 1024)
        atomicAdd(&cnt[dst[ebase + e] & (NPG - 1)], 1);
    __syncthreads();
    int deg0 = cnt[tid];
    int v = deg0;
#pragma unroll
    for (int off = 1; off < 64; off <<= 1) {
        int t = __shfl_up(v, off);
        if (lane >= off) v += t;
    }
    if (lane == 63) wsum[wid] = v;
    __syncthreads();
    if (tid < 16) {
        int sv = wsum[tid];
#pragma unroll
        for (int off = 1; off < 16; off <<= 1) {
            int t = __shfl_up(sv, off);
            if (tid >= off) sv += t;
        }
        wsum[tid] = sv;
    }
    __syncthreads();
    int excl = v + (wid ? wsum[wid - 1] : 0) - deg0;
    rowptr[g * NPG + tid] = ebase + excl;
    if (g == B_GRAPHS - 1 && tid == 0) rowptr[N_NODES] = E_TOTAL;
    cur[tid] = excl;
    __syncthreads();
    for (int e = tid; e < EPG; e += 1024) {
        int d = dst[ebase + e] & (NPG - 1);
        int p = atomicAdd(&cur[d], 1);
        scol[p] = src[ebase + e] << 9;    // pre-shifted byte offset (fsd row stride 512B)
    }
    if (tid < 64) hd[tid] = 0;
    __syncthreads();
    int dc = deg0; dc = (dc > 63) ? 63 : dc;
    atomicAdd(&hd[dc], 1);
    int4* cg = (int4*)(colb + ebase);
    const int4* cs = (const int4*)scol;
    for (int i = tid; i < EPG / 4; i += 1024) cg[i] = cs[i];
    __syncthreads();
    if (tid == 0) {
        int run = 0;
#pragma unroll 8
        for (int i = 0; i < 64; ++i) { hcur[i] = run; run += hd[i]; }
    }
    __syncthreads();
    int pos = atomicAdd(&hcur[dc], 1);
    ndpack[g * NPG + pos] = make_int2(ebase + excl, (g * NPG + tid) | (deg0 << 16));
}

// ---------------- MFMA dual GEMM, f16 single, fragment-linear W ----------------
template <int K>
__global__ __launch_bounds__(512) void k_gemm_mfma(const float* __restrict__ X,
                                                   const __half* __restrict__ Wf,
                                                   const float* __restrict__ bs, const float* __restrict__ bd,
                                                   u16* __restrict__ fsd) {
    constexpr int NC = K / 32;
    constexpr int LDK = K + 8;
    __shared__ float xsbuf[4352];
    float* xs = xsbuf;
    u16* eb = (u16*)xsbuf;
    int tid = threadIdx.x;
    int lane = tid & 63, wv = tid >> 6;
    int l15 = lane & 15, kg = lane >> 4;
    int ng = wv & 1, Tb = (wv >> 1) * 4;
    int nb = blockIdx.x * 32;

    if (K == 128) {
#pragma unroll
        for (int j = 0; j < 2; ++j) {
            int f = tid + j * 512;
            int r = f >> 5, c4 = f & 31;
            *(float4*)(xs + r * LDK + c4 * 4) = *(const float4*)(X + (size_t)(nb + r) * K + c4 * 4);
        }
    } else {
        if (tid < 256) {
            int r = tid >> 3, c4 = tid & 7;
            *(float4*)(xs + r * LDK + c4 * 4) = *(const float4*)(X + (size_t)(nb + r) * K + c4 * 4);
        }
    }
    __syncthreads();

    int ridx = ng * 16 + l15;
    FragH xf[NC];
#pragma unroll
    for (int c = 0; c < NC; ++c) {
        const float* xr = xs + ridx * LDK + c * 32 + kg * 8;
        float4 v0 = *(const float4*)xr;
        float4 v1 = *(const float4*)(xr + 4);
        xf[c].u[0] = f2h2(v0.x, v0.y);
        xf[c].u[1] = f2h2(v0.z, v0.w);
        xf[c].u[2] = f2h2(v1.x, v1.y);
        xf[c].u[3] = f2h2(v1.z, v1.w);
    }

    f32x4 acc[4];
#pragma unroll
    for (int i = 0; i < 4; ++i) acc[i] = (f32x4){0.f, 0.f, 0.f, 0.f};

#pragma unroll
    for (int i = 0; i < 4; ++i) {
        int T = Tb + i;
        const __half* wp = Wf + ((size_t)(T * NC) * 64 + lane) * 8;
#pragma unroll
        for (int c = 0; c < NC; ++c) {
            FragH wfr;
            wfr.i = *(const i32x4*)(wp + (size_t)c * 512);
            acc[i] = __builtin_amdgcn_mfma_f32_16x16x32_f16(wfr.h, xf[c].h, acc[i], 0, 0, 0);
        }
    }
    __syncthreads();

#pragma unroll
    for (int i = 0; i < 4; ++i) {
        int T = Tb + i;
        const float* bp = (T < 8) ? bs : bd;
        float4 bv = *(const float4*)(bp + (T & 7) * 16 + kg * 4);
        uint2 pk;
        pk.x = f2h2(acc[i][0] + bv.x, acc[i][1] + bv.y);
        pk.y = f2h2(acc[i][2] + bv.z, acc[i][3] + bv.w);
        int colh = (T & 7) * 16 + (T >> 3) * 128 + kg * 4;
        *(uint2*)(eb + (ng * 16 + l15) * 264 + colh) = pk;
    }
    __syncthreads();

#pragma unroll
    for (int j = 0; j < 2; ++j) {
        int f = tid + j * 512;
        int r = f >> 5, c = f & 31;
        i32x4 v = *(const i32x4*)(eb + r * 264 + c * 8);
        *(i32x4*)(fsd + (size_t)(nb + r) * 256 + c * 8) = v;
    }
}

// ---------------- GATv2 edge aggregation + head maxpool ----------------
// TWO degree-sorted quads per wave (quad wgl + quad 255-wgl: constant degree sum ->
// balanced waves, halved prologue exposures). Per quad: 4 nodes (one per quarter),
// 4 edge-chains, 2-level pipeline, no-mask fast loop (sorted quads -> masking only
// in tail), packed v_pk_fma_f16 accumulation.
__global__ __launch_bounds__(256) void k_edge(const u16* __restrict__ fsd,
                                              const int* __restrict__ colb,
                                              const int2* __restrict__ ndpack,
                                              const float* __restrict__ attn, float* __restrict__ hout) {
    int w = threadIdx.x >> 6, lane = threadIdx.x & 63;
    int bid = blockIdx.x;
    int nb = (bid & 7) * 256 + (bid >> 3);   // XCD-aware swizzle (bijective: 2048 = 8*256)
    int g2 = nb >> 5, bb = nb & 31;          // graph, block-in-graph (32 blocks/graph)
    int q = lane >> 4, s = lane & 15;
    int wgl = bb * 4 + w;                    // 0..127 wave-in-graph
    const int2* npg = ndpack + g2 * NPG;
    int2 ndA = npg[wgl * 4 + q];             // quad wgl   (low-degree half)
    int2 ndB = npg[(255 - wgl) * 4 + q];     // quad 255-wgl (high-degree half)
    const char* fsdb = (const char*)fsd;
    int nA = ndA.y & 0xFFFF, nB = ndB.y & 0xFFFF;
    // both fd gathers issued back-to-back (overlapped latency)
    i32x4 fdqA = *(const i32x4*)(fsdb + ((size_t)nA << 9) + 256 + (s << 4));
    i32x4 fdqB = *(const i32x4*)(fsdb + ((size_t)nB << 9) + 256 + (s << 4));

    // attn weights for this lane's 8 dims: head = s>>2, within-head off = (s&3)*8
    const float* ap = attn + (s >> 2) * 32 + (s & 3) * 8;
    float4 a0 = *(const float4*)ap;
    float4 a1 = *(const float4*)(ap + 4);
    const float L2E = 1.44269504089f;
    h2v av0, av1, av2, av3;
    { H2U t; t.u = f2h2(a0.x * L2E, a0.y * L2E); av0 = t.h;
      t.u = f2h2(a0.z * L2E, a0.w * L2E); av1 = t.h;
      t.u = f2h2(a1.x * L2E, a1.y * L2E); av2 = t.h;
      t.u = f2h2(a1.z * L2E, a1.w * L2E); av3 = t.h; }
    h2v neg2; neg2[0] = (_Float16)NEG; neg2[1] = (_Float16)NEG;
    const char* fb = fsdb + (s << 4);        // per-lane gather base

    auto runQuad = [&](int2 nd, i32x4 fdq) {
        int start = nd.x;
        int n = nd.y & 0xFFFF;
        int deg = nd.y >> 16;
        H2U fd0, fd1, fd2, fd3;
        fd0.u = (uint32)fdq[0]; fd1.u = (uint32)fdq[1]; fd2.u = (uint32)fdq[2]; fd3.u = (uint32)fdq[3];
        int dmin = __builtin_amdgcn_readlane(deg, 0);    // q=0 (sorted ascending)
        int dmax = __builtin_amdgcn_readlane(deg, 48);   // q=3
        int nfull = dmin >> 2;                           // iterations with ALL quarters valid
        int niter = (dmax + 3) >> 2;
        const int* cb = colb + start;

        float z = 0.f;
        uint32 c0 = 0, c1 = 0, c2 = 0, c3 = 0;

        auto gather = [&](uint32 cval) -> i32x4 {
            return *(const i32x4*)(fb + (cval & 0x01FFFE00u));   // mask keeps addr inside fsd
        };
        auto edge_core = [&](i32x4 f) -> float {
            uint32 w0 = (uint32)f[0], w1 = (uint32)f[1], w2 = (uint32)f[2], w3 = (uint32)f[3];
            float sp = dot_term(w0, fd0.h, neg2, av0, 0.f);
            sp = dot_term(w1, fd1.h, neg2, av1, sp);
            sp = dot_term(w2, fd2.h, neg2, av2, sp);
            sp = dot_term(w3, fd3.h, neg2, av3, sp);
            sp += __shfl_xor(sp, 1);
            sp += __shfl_xor(sp, 2);
            return fast_exp2(sp);
        };
        auto accum = [&](i32x4 f, float pe) {
            z += pe;
            uint32 pe2 = f2h2(pe, pe);
            pk_fma_acc(c0, (uint32)f[0], pe2);
            pk_fma_acc(c1, (uint32)f[1], pe2);
            pk_fma_acc(c2, (uint32)f[2], pe2);
            pk_fma_acc(c3, (uint32)f[3], pe2);
        };

        uint32 cnxt0 = (uint32)cb[4], cnxt1 = (uint32)cb[5], cnxt2 = (uint32)cb[6], cnxt3 = (uint32)cb[7];
        i32x4 fv0 = gather((uint32)cb[0]), fv1 = gather((uint32)cb[1]),
              fv2 = gather((uint32)cb[2]), fv3 = gather((uint32)cb[3]);

        int k = 0;
        for (; k < nfull; ++k) {           // fast loop: no masking needed
            int e = k * 4;
            i32x4 a = fv0, b = fv1, c = fv2, d = fv3;
            fv0 = gather(cnxt0); fv1 = gather(cnxt1); fv2 = gather(cnxt2); fv3 = gather(cnxt3);
            cnxt0 = (uint32)cb[e + 8]; cnxt1 = (uint32)cb[e + 9];
            cnxt2 = (uint32)cb[e + 10]; cnxt3 = (uint32)cb[e + 11];
            accum(a, edge_core(a));
            accum(b, edge_core(b));
            accum(c, edge_core(c));
            accum(d, edge_core(d));
        }
        for (; k < niter; ++k) {           // masked tail (<=~2 iterations)
            int e = k * 4;
            i32x4 a = fv0, b = fv1, c = fv2, d = fv3;
            fv0 = gather(cnxt0); fv1 = gather(cnxt1); fv2 = gather(cnxt2); fv3 = gather(cnxt3);
            cnxt0 = (uint32)cb[e + 8]; cnxt1 = (uint32)cb[e + 9];
            cnxt2 = (uint32)cb[e + 10]; cnxt3 = (uint32)cb[e + 11];
            float pa = edge_core(a); accum(a, (e + 0 < deg) ? pa : 0.f);
            float pb = edge_core(b); accum(b, (e + 1 < deg) ? pb : 0.f);
            float pc = edge_core(c); accum(c, (e + 2 < deg) ? pc : 0.f);
            float pd = edge_core(d); accum(d, (e + 3 < deg) ? pd : 0.f);
        }

        float2 u0 = h2f(c0), u1 = h2f(c1), u2 = h2f(c2), u3 = h2f(c3);
        float r = (z > 0.f) ? 1.f / z : 0.f;   // deg==0 -> output 0
        float d0 = u0.x * r, d1 = u0.y * r, d2 = u1.x * r, d3 = u1.y * r;
        float d4 = u2.x * r, d5 = u2.y * r, d6 = u3.x * r, d7 = u3.y * r;

        // maxpool over heads: coset {s, s^4, s^8, s^12} (bits 2-3)
        d0 = fmaxf(d0, __shfl_xor(d0, 4)); d0 = fmaxf(d0, __shfl_xor(d0, 8));
        d1 = fmaxf(d1, __shfl_xor(d1, 4)); d1 = fmaxf(d1, __shfl_xor(d1, 8));
        d2 = fmaxf(d2, __shfl_xor(d2, 4)); d2 = fmaxf(d2, __shfl_xor(d2, 8));
        d3 = fmaxf(d3, __shfl_xor(d3, 4)); d3 = fmaxf(d3, __shfl_xor(d3, 8));
        d4 = fmaxf(d4, __shfl_xor(d4, 4)); d4 = fmaxf(d4, __shfl_xor(d4, 8));
        d5 = fmaxf(d5, __shfl_xor(d5, 4)); d5 = fmaxf(d5, __shfl_xor(d5, 8));
        d6 = fmaxf(d6, __shfl_xor(d6, 4)); d6 = fmaxf(d6, __shfl_xor(d6, 8));
        d7 = fmaxf(d7, __shfl_xor(d7, 4)); d7 = fmaxf(d7, __shfl_xor(d7, 8));

        if (s < 4) {
            float* op = hout + ((size_t)n << 5) + (s << 3);
            *(float4*)op = make_float4(d0, d1, d2, d3);
            *(float4*)(op + 4) = make_float4(d4, d5, d6, d7);
        }
    };

    runQuad(ndA, fdqA);
    runQuad(ndB, fdqB);
}

// ---------------- global attention pooling ----------------
__global__ __launch_bounds__(256) void k_pool(const float* __restrict__ h2, const float* __restrict__ gW,
                                              const float* __restrict__ gb, float* __restrict__ out) {
    int b = blockIdx.x, tid = threadIdx.x;
    __shared__ float ga[NPG];
    __shared__ float red[256];
    __shared__ float gws[32];
    const float* hb = h2 + (size_t)b * NPG * 32;
    if (tid < 32) gws[tid] = gW[tid];
    __syncthreads();
    float gbv = gb[0];
    float lmax = -INFINITY;
    float gloc[4];
#pragma unroll
    for (int j = 0; j < 4; ++j) {
        int nl = tid + j * 256;
        const float* row = hb + nl * 32;
        float dot = 0.f;
#pragma unroll
        for (int c = 0; c < 32; c += 4) {
            float4 v = *(const float4*)(row + c);
            dot += v.x * gws[c] + v.y * gws[c + 1] + v.z * gws[c + 2] + v.w * gws[c + 3];
        }
        gloc[j] = dot + gbv;
        lmax = fmaxf(lmax, gloc[j]);
    }
    red[tid] = lmax; __syncthreads();
    for (int s2 = 128; s2 > 0; s2 >>= 1) { if (tid < s2) red[tid] = fmaxf(red[tid], red[tid + s2]); __syncthreads(); }
    float m = red[0];
    __syncthreads();
    float lsum = 0.f;
#pragma unroll
    for (int j = 0; j < 4; ++j) {
        int nl = tid + j * 256;
        float a = __expf(gloc[j] - m);
        ga[nl] = a;
        lsum += a;
    }
    red[tid] = lsum; __syncthreads();
    for (int s2 = 128; s2 > 0; s2 >>= 1) { if (tid < s2) red[tid] += red[tid + s2]; __syncthreads(); }
    float z = red[0];
    __syncthreads();
    int d = tid & 31, ng = tid >> 5;
    float acc = 0.f;
    for (int nl = ng; nl < NPG; nl += 8) acc += ga[nl] * hb[nl * 32 + d];
    red[tid] = acc; __syncthreads();
    if (tid < 32) {
        float s = red[tid];
#pragma unroll
        for (int g2 = 1; g2 < 8; ++g2) s += red[g2 * 32 + tid];
        out[b * 32 + tid] = s / z;
    }
}

extern "C" void kernel_launch(void* const* d_in, const int* in_sizes, int n_in,
                              void* d_out, int out_size, void* d_ws, size_t ws_size,
                              hipStream_t stream) {
    const float* x     = (const float*)d_in[0];
    const int*   src   = (const int*)d_in[1];
    const int*   dst   = (const int*)d_in[2];
    const float* Ws1   = (const float*)d_in[4];
    const float* bs1   = (const float*)d_in[5];
    const float* Wd1   = (const float*)d_in[6];
    const float* bd1   = (const float*)d_in[7];
    const float* attn1 = (const float*)d_in[8];
    const float* Ws2   = (const float*)d_in[9];
    const float* bs2   = (const float*)d_in[10];
    const float* Wd2   = (const float*)d_in[11];
    const float* bd2   = (const float*)d_in[12];
    const float* attn2 = (const float*)d_in[13];
    const float* gW    = (const float*)d_in[14];
    const float* gb    = (const float*)d_in[15];
    float* out = (float*)d_out;

    // workspace layout (~56 MB)
    u16* fsd   = (u16*)d_ws;                               // N*256 halfs (fs|fd interleaved)
    float* h1  = (float*)(fsd + (size_t)N_NODES * 256);    // N*32 f32
    float* h2  = h1 + (size_t)N_NODES * 32;                // N*32 f32
    int* rowptr = (int*)(h2 + (size_t)N_NODES * 32);       // N+1 (padded)
    int* colb   = rowptr + (N_NODES + 4);                  // E (pre-shifted byte offsets)
    __half* Wf1 = (__half*)(colb + E_TOTAL);               // 32768 halfs
    __half* Wf2 = Wf1 + 32768;                             // 8192 halfs
    int2* ndpack = (int2*)(Wf2 + 8192);                    // N int2 (sorted descriptors)

    // CSR build + degree-sort (blocks 0..63) + W fragment conversion (blocks 64..103)
    k_prep<<<B_GRAPHS + 40, 1024, 0, stream>>>(src, dst, rowptr, colb, ndpack,
                                               Ws1, Wd1, Ws2, Wd2, Wf1, Wf2);

    // layer 1
    k_gemm_mfma<128><<<N_NODES / 32, 512, 0, stream>>>(x, Wf1, bs1, bd1, fsd);
    k_edge<<<N_NODES / 32, 256, 0, stream>>>(fsd, colb, ndpack, attn1, h1);

    // layer 2 (overwrites fsd)
    k_gemm_mfma<32><<<N_NODES / 32, 512, 0, stream>>>(h1, Wf2, bs2, bd2, fsd);
    k_edge<<<N_NODES / 32, 256, 0, stream>>>(fsd, colb, ndpack, attn2, h2);

    // global attention pooling
    k_pool<<<B_GRAPHS, 256, 0, stream>>>(h2, gW, gb, out);
}

// Round 22
// 133.067 us; speedup vs baseline: 1.0049x; 1.0049x over previous
//
#include <hip/hip_runtime.h>
#include <hip/hip_fp16.h>
#include <math.h>

#define N_NODES 65536
#define B_GRAPHS 64
#define NPG 1024
#define EPG 16384
#define E_TOTAL (B_GRAPHS * EPG)
#define NEG 0.2f

typedef float f32x4 __attribute__((ext_vector_type(4)));
typedef _Float16 f16x8 __attribute__((ext_vector_type(8)));
typedef _Float16 h2v __attribute__((ext_vector_type(2)));
typedef int i32x4 __attribute__((ext_vector_type(4)));
typedef unsigned int uint32;
typedef unsigned short u16;

union FragH { i32x4 i; f16x8 h; uint32 u[4]; };
union H2U { uint32 u; h2v h; };

// raw v_exp_f32 (2^x) — logits bounded by construction [validated R8+]
__device__ __forceinline__ float fast_exp2(float x) {
    float r;
    asm("v_exp_f32 %0, %1" : "=v"(r) : "v"(x));
    return r;
}

__device__ __forceinline__ uint32 f2h2(float a, float b) {
    __half2 h = __float22half2_rn(make_float2(a, b));
    return *(uint32*)&h;
}
__device__ __forceinline__ float2 h2f(uint32 u) {
    __half2 h = *(__half2*)&u;
    return __half22float2(h);
}

// packed f16 accumulate: acc = fv * pe2 + acc   (v_pk_fma_f16) [validated R20]
__device__ __forceinline__ void pk_fma_acc(uint32& acc, uint32 fv, uint32 pe2) {
    asm("v_pk_fma_f16 %0, %1, %2, %0" : "+v"(acc) : "v"(fv), "v"(pe2));
}

// e = fv + fd; e = max(e, NEG*e); sp += dot2(e, av)   (f32 accumulate) [validated R8+]
__device__ __forceinline__ float dot_term(uint32 fvu, h2v fdv, h2v neg2, h2v av, float accum) {
    H2U fv; fv.u = fvu;
    h2v e = fv.h + fdv;                  // v_pk_add_f16
    h2v en = e * neg2;                   // v_pk_mul_f16
    h2v em;
    asm("v_pk_max_f16 %0, %1, %2" : "=v"(em) : "v"(e), "v"(en));
    float sp;
    asm("v_dot2_f32_f16 %0, %1, %2, %3" : "=v"(sp) : "v"(em), "v"(av), "v"(accum));
    return sp;
}

// ---------------- prep: CSR count-sort + degree-sorted descriptors + W frag conv ----------------
__global__ __launch_bounds__(1024) void k_prep(const int* __restrict__ src, const int* __restrict__ dst,
                                               int* __restrict__ rowptr, int* __restrict__ colb,
                                               int2* __restrict__ ndpack,
                                               const float* __restrict__ Ws1, const float* __restrict__ Wd1,
                                               const float* __restrict__ Ws2, const float* __restrict__ Wd2,
                                               __half* __restrict__ Wf1, __half* __restrict__ Wf2) {
    __shared__ int cnt[NPG];
    __shared__ int cur[NPG];
    __shared__ int scol[EPG];   // 64KB
    __shared__ int wsum[16];
    __shared__ int hd[64];
    __shared__ int hcur[64];
    if (blockIdx.x >= B_GRAPHS) {
        int id = (blockIdx.x - B_GRAPHS) * 1024 + threadIdx.x;
        if (id < 32768) {
            int j = id & 7, l = (id >> 3) & 63, c = (id >> 9) & 3, T = id >> 11;
            int k = c * 32 + (l >> 4) * 8 + j;
            int n = (T & 7) * 16 + (l & 15);
            const float* W = (T < 8) ? Ws1 : Wd1;
            Wf1[id] = __float2half_rn(W[k * 128 + n]);
        } else if (id < 40960) {
            int rem = id - 32768;
            int j = rem & 7, l = (rem >> 3) & 63, T = rem >> 9;
            int k = (l >> 4) * 8 + j;
            int n = (T & 7) * 16 + (l & 15);
            const float* W = (T < 8) ? Ws2 : Wd2;
            Wf2[rem] = __float2half_rn(W[k * 128 + n]);
        }
        return;
    }
    int g = blockIdx.x, tid = threadIdx.x;
    int lane = tid & 63, wid = tid >> 6;
    int ebase = g * EPG;
    cnt[tid] = 0;
    __syncthreads();
    for (int e = tid; e < EPG; e += 1024)
        atomicAdd(&cnt[dst[ebase + e] & (NPG - 1)], 1);
    __syncthreads();
    int deg0 = cnt[tid];
    int v = deg0;
#pragma unroll
    for (int off = 1; off < 64; off <<= 1) {
        int t = __shfl_up(v, off);
        if (lane >= off) v += t;
    }
    if (lane == 63) wsum[wid] = v;
    __syncthreads();
    if (tid < 16) {
        int sv = wsum[tid];
#pragma unroll
        for (int off = 1; off < 16; off <<= 1) {
            int t = __shfl_up(sv, off);
            if (tid >= off) sv += t;
        }
        wsum[tid] = sv;
    }
    __syncthreads();
    int excl = v + (wid ? wsum[wid - 1] : 0) - deg0;
    rowptr[g * NPG + tid] = ebase + excl;
    if (g == B_GRAPHS - 1 && tid == 0) rowptr[N_NODES] = E_TOTAL;
    cur[tid] = excl;
    __syncthreads();
    for (int e = tid; e < EPG; e += 1024) {
        int d = dst[ebase + e] & (NPG - 1);
        int p = atomicAdd(&cur[d], 1);
        scol[p] = src[ebase + e] << 9;    // pre-shifted byte offset (fsd row stride 512B)
    }
    if (tid < 64) hd[tid] = 0;
    __syncthreads();
    int dc = deg0; dc = (dc > 63) ? 63 : dc;
    atomicAdd(&hd[dc], 1);
    int4* cg = (int4*)(colb + ebase);
    const int4* cs = (const int4*)scol;
    for (int i = tid; i < EPG / 4; i += 1024) cg[i] = cs[i];
    __syncthreads();
    if (tid == 0) {
        int run = 0;
#pragma unroll 8
        for (int i = 0; i < 64; ++i) { hcur[i] = run; run += hd[i]; }
    }
    __syncthreads();
    int pos = atomicAdd(&hcur[dc], 1);
    ndpack[g * NPG + pos] = make_int2(ebase + excl, (g * NPG + tid) | (deg0 << 16));
}

// ---------------- MFMA dual GEMM, f16 single, fragment-linear W ----------------
template <int K>
__global__ __launch_bounds__(512) void k_gemm_mfma(const float* __restrict__ X,
                                                   const __half* __restrict__ Wf,
                                                   const float* __restrict__ bs, const float* __restrict__ bd,
                                                   u16* __restrict__ fsd) {
    constexpr int NC = K / 32;
    constexpr int LDK = K + 8;
    __shared__ float xsbuf[4352];
    float* xs = xsbuf;
    u16* eb = (u16*)xsbuf;
    int tid = threadIdx.x;
    int lane = tid & 63, wv = tid >> 6;
    int l15 = lane & 15, kg = lane >> 4;
    int ng = wv & 1, Tb = (wv >> 1) * 4;
    int nb = blockIdx.x * 32;

    if (K == 128) {
#pragma unroll
        for (int j = 0; j < 2; ++j) {
            int f = tid + j * 512;
            int r = f >> 5, c4 = f & 31;
            *(float4*)(xs + r * LDK + c4 * 4) = *(const float4*)(X + (size_t)(nb + r) * K + c4 * 4);
        }
    } else {
        if (tid < 256) {
            int r = tid >> 3, c4 = tid & 7;
            *(float4*)(xs + r * LDK + c4 * 4) = *(const float4*)(X + (size_t)(nb + r) * K + c4 * 4);
        }
    }
    __syncthreads();

    int ridx = ng * 16 + l15;
    FragH xf[NC];
#pragma unroll
    for (int c = 0; c < NC; ++c) {
        const float* xr = xs + ridx * LDK + c * 32 + kg * 8;
        float4 v0 = *(const float4*)xr;
        float4 v1 = *(const float4*)(xr + 4);
        xf[c].u[0] = f2h2(v0.x, v0.y);
        xf[c].u[1] = f2h2(v0.z, v0.w);
        xf[c].u[2] = f2h2(v1.x, v1.y);
        xf[c].u[3] = f2h2(v1.z, v1.w);
    }

    f32x4 acc[4];
#pragma unroll
    for (int i = 0; i < 4; ++i) acc[i] = (f32x4){0.f, 0.f, 0.f, 0.f};

#pragma unroll
    for (int i = 0; i < 4; ++i) {
        int T = Tb + i;
        const __half* wp = Wf + ((size_t)(T * NC) * 64 + lane) * 8;
#pragma unroll
        for (int c = 0; c < NC; ++c) {
            FragH wfr;
            wfr.i = *(const i32x4*)(wp + (size_t)c * 512);
            acc[i] = __builtin_amdgcn_mfma_f32_16x16x32_f16(wfr.h, xf[c].h, acc[i], 0, 0, 0);
        }
    }
    __syncthreads();

#pragma unroll
    for (int i = 0; i < 4; ++i) {
        int T = Tb + i;
        const float* bp = (T < 8) ? bs : bd;
        float4 bv = *(const float4*)(bp + (T & 7) * 16 + kg * 4);
        uint2 pk;
        pk.x = f2h2(acc[i][0] + bv.x, acc[i][1] + bv.y);
        pk.y = f2h2(acc[i][2] + bv.z, acc[i][3] + bv.w);
        int colh = (T & 7) * 16 + (T >> 3) * 128 + kg * 4;
        *(uint2*)(eb + (ng * 16 + l15) * 264 + colh) = pk;
    }
    __syncthreads();

#pragma unroll
    for (int j = 0; j < 2; ++j) {
        int f = tid + j * 512;
        int r = f >> 5, c = f & 31;
        i32x4 v = *(const i32x4*)(eb + r * 264 + c * 8);
        *(i32x4*)(fsd + (size_t)(nb + r) * 256 + c * 8) = v;
    }
}

// ---------------- GATv2 edge aggregation + head maxpool ----------------
// R20 structure (one degree-sorted quad per wave, balanced quad->block map,
// packed int2 descriptors, 4 edge-chains, 2-level pipeline, pk_fma accumulate)
// + no-mask fast loop (sorted quads -> masking only in the tail iterations)
// + readlane-based min/max degree (lane 0 = q0 min, lane 48 = q3 max).
__global__ __launch_bounds__(256) void k_edge(const u16* __restrict__ fsd,
                                              const int* __restrict__ colb,
                                              const int2* __restrict__ ndpack,
                                              const float* __restrict__ attn, float* __restrict__ hout) {
    int w = threadIdx.x >> 6, lane = threadIdx.x & 63;
    int bid = blockIdx.x;
    int nb = (bid & 7) * 512 + (bid >> 3);   // XCD-aware swizzle (8 graphs = 4MB fsd per XCD L2)
    int g2 = nb >> 6, bb = nb & 63;
    int q = lane >> 4, s = lane & 15;
    int wgl = bb * 4 + w;
    int quad = (wgl & 3) * 64 + (wgl >> 2);  // balanced bijection over sorted quads
    int2 nd = ndpack[g2 * NPG + quad * 4 + q];
    int start = nd.x;
    int n = nd.y & 0xFFFF;
    int deg = nd.y >> 16;
    const char* fsdb = (const char*)fsd;

    const float* ap = attn + (s >> 2) * 32 + (s & 3) * 8;
    float4 a0 = *(const float4*)ap;
    float4 a1 = *(const float4*)(ap + 4);
    const float L2E = 1.44269504089f;
    h2v av0, av1, av2, av3;
    { H2U t; t.u = f2h2(a0.x * L2E, a0.y * L2E); av0 = t.h;
      t.u = f2h2(a0.z * L2E, a0.w * L2E); av1 = t.h;
      t.u = f2h2(a1.x * L2E, a1.y * L2E); av2 = t.h;
      t.u = f2h2(a1.z * L2E, a1.w * L2E); av3 = t.h; }
    h2v neg2; neg2[0] = (_Float16)NEG; neg2[1] = (_Float16)NEG;

    i32x4 fdq = *(const i32x4*)(fsdb + ((size_t)n << 9) + 256 + (s << 4));
    H2U fd0, fd1, fd2, fd3;
    fd0.u = (uint32)fdq[0]; fd1.u = (uint32)fdq[1]; fd2.u = (uint32)fdq[2]; fd3.u = (uint32)fdq[3];

    // sorted quad: q=0 (lane 0) has min degree, q=3 (lane 48) has max degree
    int dmin = __builtin_amdgcn_readlane(deg, 0);
    int dmax = __builtin_amdgcn_readlane(deg, 48);
    int nfull = dmin >> 2;                 // iterations where ALL quarters valid
    int niter = (dmax + 3) >> 2;

    const char* fb = fsdb + (s << 4);
    const int* cb = colb + start;

    float z = 0.f;
    uint32 c0 = 0, c1 = 0, c2 = 0, c3 = 0;    // packed f16 accumulators (dims 2d,2d+1)

    auto gather = [&](uint32 cval) -> i32x4 {
        return *(const i32x4*)(fb + (cval & 0x01FFFE00u));
    };
    auto edge_core = [&](i32x4 f) -> float {
        uint32 w0 = (uint32)f[0], w1 = (uint32)f[1], w2 = (uint32)f[2], w3 = (uint32)f[3];
        float sp = dot_term(w0, fd0.h, neg2, av0, 0.f);
        sp = dot_term(w1, fd1.h, neg2, av1, sp);
        sp = dot_term(w2, fd2.h, neg2, av2, sp);
        sp = dot_term(w3, fd3.h, neg2, av3, sp);
        sp += __shfl_xor(sp, 1);
        sp += __shfl_xor(sp, 2);
        return fast_exp2(sp);
    };
    auto accum = [&](i32x4 f, float pe) {
        z += pe;
        uint32 pe2 = f2h2(pe, pe);            // v_cvt_pkrtz
        pk_fma_acc(c0, (uint32)f[0], pe2);
        pk_fma_acc(c1, (uint32)f[1], pe2);
        pk_fma_acc(c2, (uint32)f[2], pe2);
        pk_fma_acc(c3, (uint32)f[3], pe2);
    };

    uint32 cnxt0 = (uint32)cb[4], cnxt1 = (uint32)cb[5], cnxt2 = (uint32)cb[6], cnxt3 = (uint32)cb[7];
    i32x4 fv0 = gather((uint32)cb[0]), fv1 = gather((uint32)cb[1]),
          fv2 = gather((uint32)cb[2]), fv3 = gather((uint32)cb[3]);

    int k = 0;
    for (; k < nfull; ++k) {               // fast loop: all quarters valid, no masking
        int e = k * 4;
        i32x4 a = fv0, b = fv1, c = fv2, d = fv3;
        fv0 = gather(cnxt0); fv1 = gather(cnxt1); fv2 = gather(cnxt2); fv3 = gather(cnxt3);
        cnxt0 = (uint32)cb[e + 8]; cnxt1 = (uint32)cb[e + 9];
        cnxt2 = (uint32)cb[e + 10]; cnxt3 = (uint32)cb[e + 11];
        accum(a, edge_core(a));
        accum(b, edge_core(b));
        accum(c, edge_core(c));
        accum(d, edge_core(d));
    }
    for (; k < niter; ++k) {               // masked tail (few iterations)
        int e = k * 4;
        i32x4 a = fv0, b = fv1, c = fv2, d = fv3;
        fv0 = gather(cnxt0); fv1 = gather(cnxt1); fv2 = gather(cnxt2); fv3 = gather(cnxt3);
        cnxt0 = (uint32)cb[e + 8]; cnxt1 = (uint32)cb[e + 9];
        cnxt2 = (uint32)cb[e + 10]; cnxt3 = (uint32)cb[e + 11];
        float pa = edge_core(a); accum(a, (e + 0 < deg) ? pa : 0.f);
        float pb = edge_core(b); accum(b, (e + 1 < deg) ? pb : 0.f);
        float pc = edge_core(c); accum(c, (e + 2 < deg) ? pc : 0.f);
        float pd = edge_core(d); accum(d, (e + 3 < deg) ? pd : 0.f);
    }

    // unpack packed accumulators to f32
    float2 u0 = h2f(c0), u1 = h2f(c1), u2 = h2f(c2), u3 = h2f(c3);
    float r = (z > 0.f) ? 1.f / z : 0.f;   // deg==0 -> output 0
    float d0 = u0.x * r, d1 = u0.y * r, d2 = u1.x * r, d3 = u1.y * r;
    float d4 = u2.x * r, d5 = u2.y * r, d6 = u3.x * r, d7 = u3.y * r;

    // maxpool over heads: coset {s, s^4, s^8, s^12} within the quarter (bits 2-3)
    d0 = fmaxf(d0, __shfl_xor(d0, 4)); d0 = fmaxf(d0, __shfl_xor(d0, 8));
    d1 = fmaxf(d1, __shfl_xor(d1, 4)); d1 = fmaxf(d1, __shfl_xor(d1, 8));
    d2 = fmaxf(d2, __shfl_xor(d2, 4)); d2 = fmaxf(d2, __shfl_xor(d2, 8));
    d3 = fmaxf(d3, __shfl_xor(d3, 4)); d3 = fmaxf(d3, __shfl_xor(d3, 8));
    d4 = fmaxf(d4, __shfl_xor(d4, 4)); d4 = fmaxf(d4, __shfl_xor(d4, 8));
    d5 = fmaxf(d5, __shfl_xor(d5, 4)); d5 = fmaxf(d5, __shfl_xor(d5, 8));
    d6 = fmaxf(d6, __shfl_xor(d6, 4)); d6 = fmaxf(d6, __shfl_xor(d6, 8));
    d7 = fmaxf(d7, __shfl_xor(d7, 4)); d7 = fmaxf(d7, __shfl_xor(d7, 8));

    if (s < 4) {
        float* op = hout + ((size_t)n << 5) + (s << 3);
        *(float4*)op = make_float4(d0, d1, d2, d3);
        *(float4*)(op + 4) = make_float4(d4, d5, d6, d7);
    }
}

// ---------------- global attention pooling ----------------
__global__ __launch_bounds__(256) void k_pool(const float* __restrict__ h2, const float* __restrict__ gW,
                                              const float* __restrict__ gb, float* __restrict__ out) {
    int b = blockIdx.x, tid = threadIdx.x;
    __shared__ float ga[NPG];
    __shared__ float red[256];
    __shared__ float gws[32];
    const float* hb = h2 + (size_t)b * NPG * 32;
    if (tid < 32) gws[tid] = gW[tid];
    __syncthreads();
    float gbv = gb[0];
    float lmax = -INFINITY;
    float gloc[4];
#pragma unroll
    for (int j = 0; j < 4; ++j) {
        int nl = tid + j * 256;
        const float* row = hb + nl * 32;
        float dot = 0.f;
#pragma unroll
        for (int c = 0; c < 32; c += 4) {
            float4 v = *(const float4*)(row + c);
            dot += v.x * gws[c] + v.y * gws[c + 1] + v.z * gws[c + 2] + v.w * gws[c + 3];
        }
        gloc[j] = dot + gbv;
        lmax = fmaxf(lmax, gloc[j]);
    }
    red[tid] = lmax; __syncthreads();
    for (int s2 = 128; s2 > 0; s2 >>= 1) { if (tid < s2) red[tid] = fmaxf(red[tid], red[tid + s2]); __syncthreads(); }
    float m = red[0];
    __syncthreads();
    float lsum = 0.f;
#pragma unroll
    for (int j = 0; j < 4; ++j) {
        int nl = tid + j * 256;
        float a = __expf(gloc[j] - m);
        ga[nl] = a;
        lsum += a;
    }
    red[tid] = lsum; __syncthreads();
    for (int s2 = 128; s2 > 0; s2 >>= 1) { if (tid < s2) red[tid] += red[tid + s2]; __syncthreads(); }
    float z = red[0];
    __syncthreads();
    int d = tid & 31, ng = tid >> 5;
    float acc = 0.f;
    for (int nl = ng; nl < NPG; nl += 8) acc += ga[nl] * hb[nl * 32 + d];
    red[tid] = acc; __syncthreads();
    if (tid < 32) {
        float s = red[tid];
#pragma unroll
        for (int g2 = 1; g2 < 8; ++g2) s += red[g2 * 32 + tid];
        out[b * 32 + tid] = s / z;
    }
}

extern "C" void kernel_launch(void* const* d_in, const int* in_sizes, int n_in,
                              void* d_out, int out_size, void* d_ws, size_t ws_size,
                              hipStream_t stream) {
    const float* x     = (const float*)d_in[0];
    const int*   src   = (const int*)d_in[1];
    const int*   dst   = (const int*)d_in[2];
    const float* Ws1   = (const float*)d_in[4];
    const float* bs1   = (const float*)d_in[5];
    const float* Wd1   = (const float*)d_in[6];
    const float* bd1   = (const float*)d_in[7];
    const float* attn1 = (const float*)d_in[8];
    const float* Ws2   = (const float*)d_in[9];
    const float* bs2   = (const float*)d_in[10];
    const float* Wd2   = (const float*)d_in[11];
    const float* bd2   = (const float*)d_in[12];
    const float* attn2 = (const float*)d_in[13];
    const float* gW    = (const float*)d_in[14];
    const float* gb    = (const float*)d_in[15];
    float* out = (float*)d_out;

    // workspace layout (~56 MB)
    u16* fsd   = (u16*)d_ws;                               // N*256 halfs (fs|fd interleaved)
    float* h1  = (float*)(fsd + (size_t)N_NODES * 256);    // N*32 f32
    float* h2  = h1 + (size_t)N_NODES * 32;                // N*32 f32
    int* rowptr = (int*)(h2 + (size_t)N_NODES * 32);       // N+1 (padded)
    int* colb   = rowptr + (N_NODES + 4);                  // E (pre-shifted byte offsets)
    __half* Wf1 = (__half*)(colb + E_TOTAL);               // 32768 halfs
    __half* Wf2 = Wf1 + 32768;                             // 8192 halfs
    int2* ndpack = (int2*)(Wf2 + 8192);                    // N int2 (sorted descriptors)

    // CSR build + degree-sort (blocks 0..63) + W fragment conversion (blocks 64..103)
    k_prep<<<B_GRAPHS + 40, 1024, 0, stream>>>(src, dst, rowptr, colb, ndpack,
                                               Ws1, Wd1, Ws2, Wd2, Wf1, Wf2);

    // layer 1
    k_gemm_mfma<128><<<N_NODES / 32, 512, 0, stream>>>(x, Wf1, bs1, bd1, fsd);
    k_edge<<<N_NODES / 16, 256, 0, stream>>>(fsd, colb, ndpack, attn1, h1);

    // layer 2 (overwrites fsd)
    k_gemm_mfma<32><<<N_NODES / 32, 512, 0, stream>>>(h1, Wf2, bs2, bd2, fsd);
    k_edge<<<N_NODES / 16, 256, 0, stream>>>(fsd, colb, ndpack, attn2, h2);

    // global attention pooling
    k_pool<<<B_GRAPHS, 256, 0, stream>>>(h2, gW, gb, out);
}

// Round 23
// 129.370 us; speedup vs baseline: 1.0336x; 1.0286x over previous
//
#include <hip/hip_runtime.h>
#include <hip/hip_fp16.h>
#include <math.h>

#define N_NODES 65536
#define B_GRAPHS 64
#define NPG 1024
#define EPG 16384
#define E_TOTAL (B_GRAPHS * EPG)
#define NEG 0.2f

typedef float f32x4 __attribute__((ext_vector_type(4)));
typedef _Float16 f16x8 __attribute__((ext_vector_type(8)));
typedef _Float16 h2v __attribute__((ext_vector_type(2)));
typedef int i32x4 __attribute__((ext_vector_type(4)));
typedef unsigned int uint32;
typedef unsigned short u16;

union FragH { i32x4 i; f16x8 h; uint32 u[4]; };
union H2U { uint32 u; h2v h; };

// raw v_exp_f32 (2^x) — logits bounded by construction [validated R8+]
__device__ __forceinline__ float fast_exp2(float x) {
    float r;
    asm("v_exp_f32 %0, %1" : "=v"(r) : "v"(x));
    return r;
}

__device__ __forceinline__ uint32 f2h2(float a, float b) {
    __half2 h = __float22half2_rn(make_float2(a, b));
    return *(uint32*)&h;
}
__device__ __forceinline__ float2 h2f(uint32 u) {
    __half2 h = *(__half2*)&u;
    return __half22float2(h);
}

// packed f16 accumulate: acc = fv * pe2 + acc   (v_pk_fma_f16) [validated R20]
__device__ __forceinline__ void pk_fma_acc(uint32& acc, uint32 fv, uint32 pe2) {
    asm("v_pk_fma_f16 %0, %1, %2, %0" : "+v"(acc) : "v"(fv), "v"(pe2));
}

// e = fv + fd; e = max(e, NEG*e); sp += dot2(e, av)   (f32 accumulate) [validated R8+]
__device__ __forceinline__ float dot_term(uint32 fvu, h2v fdv, h2v neg2, h2v av, float accum) {
    H2U fv; fv.u = fvu;
    h2v e = fv.h + fdv;                  // v_pk_add_f16
    h2v en = e * neg2;                   // v_pk_mul_f16
    h2v em;
    asm("v_pk_max_f16 %0, %1, %2" : "=v"(em) : "v"(e), "v"(en));
    float sp;
    asm("v_dot2_f32_f16 %0, %1, %2, %3" : "=v"(sp) : "v"(em), "v"(av), "v"(accum));
    return sp;
}

// ---------------- prep: CSR count-sort + degree-sorted descriptors + W frag conv ----------------
__global__ __launch_bounds__(1024) void k_prep(const int* __restrict__ src, const int* __restrict__ dst,
                                               int* __restrict__ rowptr, int* __restrict__ colb,
                                               int2* __restrict__ ndpack,
                                               const float* __restrict__ Ws1, const float* __restrict__ Wd1,
                                               const float* __restrict__ Ws2, const float* __restrict__ Wd2,
                                               __half* __restrict__ Wf1, __half* __restrict__ Wf2) {
    __shared__ int cnt[NPG];
    __shared__ int cur[NPG];
    __shared__ int scol[EPG];   // 64KB
    __shared__ int wsum[16];
    __shared__ int hd[64];
    __shared__ int hcur[64];
    if (blockIdx.x >= B_GRAPHS) {
        int id = (blockIdx.x - B_GRAPHS) * 1024 + threadIdx.x;
        if (id < 32768) {
            int j = id & 7, l = (id >> 3) & 63, c = (id >> 9) & 3, T = id >> 11;
            int k = c * 32 + (l >> 4) * 8 + j;
            int n = (T & 7) * 16 + (l & 15);
            const float* W = (T < 8) ? Ws1 : Wd1;
            Wf1[id] = __float2half_rn(W[k * 128 + n]);
        } else if (id < 40960) {
            int rem = id - 32768;
            int j = rem & 7, l = (rem >> 3) & 63, T = rem >> 9;
            int k = (l >> 4) * 8 + j;
            int n = (T & 7) * 16 + (l & 15);
            const float* W = (T < 8) ? Ws2 : Wd2;
            Wf2[rem] = __float2half_rn(W[k * 128 + n]);
        }
        return;
    }
    int g = blockIdx.x, tid = threadIdx.x;
    int lane = tid & 63, wid = tid >> 6;
    int ebase = g * EPG;
    cnt[tid] = 0;
    __syncthreads();
    for (int e = tid; e < EPG; e += 1024)
        atomicAdd(&cnt[dst[ebase + e] & (NPG - 1)], 1);
    __syncthreads();
    int deg0 = cnt[tid];
    int v = deg0;
#pragma unroll
    for (int off = 1; off < 64; off <<= 1) {
        int t = __shfl_up(v, off);
        if (lane >= off) v += t;
    }
    if (lane == 63) wsum[wid] = v;
    __syncthreads();
    if (tid < 16) {
        int sv = wsum[tid];
#pragma unroll
        for (int off = 1; off < 16; off <<= 1) {
            int t = __shfl_up(sv, off);
            if (tid >= off) sv += t;
        }
        wsum[tid] = sv;
    }
    __syncthreads();
    int excl = v + (wid ? wsum[wid - 1] : 0) - deg0;
    rowptr[g * NPG + tid] = ebase + excl;
    if (g == B_GRAPHS - 1 && tid == 0) rowptr[N_NODES] = E_TOTAL;
    cur[tid] = excl;
    __syncthreads();
    for (int e = tid; e < EPG; e += 1024) {
        int d = dst[ebase + e] & (NPG - 1);
        int p = atomicAdd(&cur[d], 1);
        scol[p] = src[ebase + e] << 9;    // pre-shifted byte offset (fsd row stride 512B)
    }
    if (tid < 64) hd[tid] = 0;
    __syncthreads();
    int dc = deg0; dc = (dc > 63) ? 63 : dc;
    atomicAdd(&hd[dc], 1);
    int4* cg = (int4*)(colb + ebase);
    const int4* cs = (const int4*)scol;
    for (int i = tid; i < EPG / 4; i += 1024) cg[i] = cs[i];
    __syncthreads();
    if (tid == 0) {
        int run = 0;
#pragma unroll 8
        for (int i = 0; i < 64; ++i) { hcur[i] = run; run += hd[i]; }
    }
    __syncthreads();
    int pos = atomicAdd(&hcur[dc], 1);
    ndpack[g * NPG + pos] = make_int2(ebase + excl, (g * NPG + tid) | (deg0 << 16));
}

// ---------------- MFMA dual GEMM, f16 single, fragment-linear W ----------------
template <int K>
__global__ __launch_bounds__(512) void k_gemm_mfma(const float* __restrict__ X,
                                                   const __half* __restrict__ Wf,
                                                   const float* __restrict__ bs, const float* __restrict__ bd,
                                                   u16* __restrict__ fsd) {
    constexpr int NC = K / 32;
    constexpr int LDK = K + 8;
    __shared__ float xsbuf[4352];
    float* xs = xsbuf;
    u16* eb = (u16*)xsbuf;
    int tid = threadIdx.x;
    int lane = tid & 63, wv = tid >> 6;
    int l15 = lane & 15, kg = lane >> 4;
    int ng = wv & 1, Tb = (wv >> 1) * 4;
    int nb = blockIdx.x * 32;

    if (K == 128) {
#pragma unroll
        for (int j = 0; j < 2; ++j) {
            int f = tid + j * 512;
            int r = f >> 5, c4 = f & 31;
            *(float4*)(xs + r * LDK + c4 * 4) = *(const float4*)(X + (size_t)(nb + r) * K + c4 * 4);
        }
    } else {
        if (tid < 256) {
            int r = tid >> 3, c4 = tid & 7;
            *(float4*)(xs + r * LDK + c4 * 4) = *(const float4*)(X + (size_t)(nb + r) * K + c4 * 4);
        }
    }
    __syncthreads();

    int ridx = ng * 16 + l15;
    FragH xf[NC];
#pragma unroll
    for (int c = 0; c < NC; ++c) {
        const float* xr = xs + ridx * LDK + c * 32 + kg * 8;
        float4 v0 = *(const float4*)xr;
        float4 v1 = *(const float4*)(xr + 4);
        xf[c].u[0] = f2h2(v0.x, v0.y);
        xf[c].u[1] = f2h2(v0.z, v0.w);
        xf[c].u[2] = f2h2(v1.x, v1.y);
        xf[c].u[3] = f2h2(v1.z, v1.w);
    }

    f32x4 acc[4];
#pragma unroll
    for (int i = 0; i < 4; ++i) acc[i] = (f32x4){0.f, 0.f, 0.f, 0.f};

#pragma unroll
    for (int i = 0; i < 4; ++i) {
        int T = Tb + i;
        const __half* wp = Wf + ((size_t)(T * NC) * 64 + lane) * 8;
#pragma unroll
        for (int c = 0; c < NC; ++c) {
            FragH wfr;
            wfr.i = *(const i32x4*)(wp + (size_t)c * 512);
            acc[i] = __builtin_amdgcn_mfma_f32_16x16x32_f16(wfr.h, xf[c].h, acc[i], 0, 0, 0);
        }
    }
    __syncthreads();

#pragma unroll
    for (int i = 0; i < 4; ++i) {
        int T = Tb + i;
        const float* bp = (T < 8) ? bs : bd;
        float4 bv = *(const float4*)(bp + (T & 7) * 16 + kg * 4);
        uint2 pk;
        pk.x = f2h2(acc[i][0] + bv.x, acc[i][1] + bv.y);
        pk.y = f2h2(acc[i][2] + bv.z, acc[i][3] + bv.w);
        int colh = (T & 7) * 16 + (T >> 3) * 128 + kg * 4;
        *(uint2*)(eb + (ng * 16 + l15) * 264 + colh) = pk;
    }
    __syncthreads();

#pragma unroll
    for (int j = 0; j < 2; ++j) {
        int f = tid + j * 512;
        int r = f >> 5, c = f & 31;
        i32x4 v = *(const i32x4*)(eb + r * 264 + c * 8);
        *(i32x4*)(fsd + (size_t)(nb + r) * 256 + c * 8) = v;
    }
}

// ---------------- GATv2 edge aggregation + head maxpool ----------------
// 4 nodes per wave via degree-sorted quads, balanced quad->block map, packed int2
// descriptors, 4 edge-chains/quarter, 2-level pipeline, unconditional col loads,
// packed v_pk_fma_f16 numerator accumulation. [R20 best-known configuration]
__global__ __launch_bounds__(256) void k_edge(const u16* __restrict__ fsd,
                                              const int* __restrict__ colb,
                                              const int2* __restrict__ ndpack,
                                              const float* __restrict__ attn, float* __restrict__ hout) {
    int w = threadIdx.x >> 6, lane = threadIdx.x & 63;
    int bid = blockIdx.x;
    int nb = (bid & 7) * 512 + (bid >> 3);   // XCD-aware swizzle (8 graphs = 4MB fsd per XCD L2)
    int g2 = nb >> 6, bb = nb & 63;
    int q = lane >> 4, s = lane & 15;
    int wgl = bb * 4 + w;
    int quad = (wgl & 3) * 64 + (wgl >> 2);  // balanced bijection over sorted quads
    int2 nd = ndpack[g2 * NPG + quad * 4 + q];
    int start = nd.x;
    int n = nd.y & 0xFFFF;
    int deg = nd.y >> 16;
    const char* fsdb = (const char*)fsd;

    const float* ap = attn + (s >> 2) * 32 + (s & 3) * 8;
    float4 a0 = *(const float4*)ap;
    float4 a1 = *(const float4*)(ap + 4);
    const float L2E = 1.44269504089f;
    h2v av0, av1, av2, av3;
    { H2U t; t.u = f2h2(a0.x * L2E, a0.y * L2E); av0 = t.h;
      t.u = f2h2(a0.z * L2E, a0.w * L2E); av1 = t.h;
      t.u = f2h2(a1.x * L2E, a1.y * L2E); av2 = t.h;
      t.u = f2h2(a1.z * L2E, a1.w * L2E); av3 = t.h; }
    h2v neg2; neg2[0] = (_Float16)NEG; neg2[1] = (_Float16)NEG;

    i32x4 fdq = *(const i32x4*)(fsdb + ((size_t)n << 9) + 256 + (s << 4));
    H2U fd0, fd1, fd2, fd3;
    fd0.u = (uint32)fdq[0]; fd1.u = (uint32)fdq[1]; fd2.u = (uint32)fdq[2]; fd3.u = (uint32)fdq[3];

    int m = deg;
    { int t16 = __shfl_xor(m, 16); m = (t16 > m) ? t16 : m;
      int t32 = __shfl_xor(m, 32); m = (t32 > m) ? t32 : m; }
    int niter = (__builtin_amdgcn_readfirstlane(m) + 3) >> 2;

    const char* fb = fsdb + (s << 4);
    const int* cb = colb + start;

    float z = 0.f;
    uint32 c0 = 0, c1 = 0, c2 = 0, c3 = 0;    // packed f16 accumulators (dims 2d,2d+1)

    auto gather = [&](uint32 cval) -> i32x4 {
        return *(const i32x4*)(fb + (cval & 0x01FFFE00u));
    };

    auto proc = [&](i32x4 f, int e) {
        uint32 w0 = (uint32)f[0], w1 = (uint32)f[1], w2 = (uint32)f[2], w3 = (uint32)f[3];
        float sp = dot_term(w0, fd0.h, neg2, av0, 0.f);
        sp = dot_term(w1, fd1.h, neg2, av1, sp);
        sp = dot_term(w2, fd2.h, neg2, av2, sp);
        sp = dot_term(w3, fd3.h, neg2, av3, sp);
        sp += __shfl_xor(sp, 1);
        sp += __shfl_xor(sp, 2);
        float pe = fast_exp2(sp);
        pe = (e < deg) ? pe : 0.f;
        z += pe;
        uint32 pe2 = f2h2(pe, pe);            // v_cvt_pkrtz
        pk_fma_acc(c0, w0, pe2);
        pk_fma_acc(c1, w1, pe2);
        pk_fma_acc(c2, w2, pe2);
        pk_fma_acc(c3, w3, pe2);
    };

    uint32 cnxt0 = (uint32)cb[4], cnxt1 = (uint32)cb[5], cnxt2 = (uint32)cb[6], cnxt3 = (uint32)cb[7];
    i32x4 fv0 = gather((uint32)cb[0]), fv1 = gather((uint32)cb[1]),
          fv2 = gather((uint32)cb[2]), fv3 = gather((uint32)cb[3]);

    for (int k = 0; k < niter; ++k) {
        int e = k * 4;
        i32x4 a = fv0, b = fv1, c = fv2, d = fv3;
        fv0 = gather(cnxt0); fv1 = gather(cnxt1); fv2 = gather(cnxt2); fv3 = gather(cnxt3);
        cnxt0 = (uint32)cb[e + 8]; cnxt1 = (uint32)cb[e + 9];
        cnxt2 = (uint32)cb[e + 10]; cnxt3 = (uint32)cb[e + 11];
        proc(a, e + 0);
        proc(b, e + 1);
        proc(c, e + 2);
        proc(d, e + 3);
    }

    // unpack packed accumulators to f32
    float2 u0 = h2f(c0), u1 = h2f(c1), u2 = h2f(c2), u3 = h2f(c3);
    float r = (z > 0.f) ? 1.f / z : 0.f;   // deg==0 -> output 0
    float d0 = u0.x * r, d1 = u0.y * r, d2 = u1.x * r, d3 = u1.y * r;
    float d4 = u2.x * r, d5 = u2.y * r, d6 = u3.x * r, d7 = u3.y * r;

    // maxpool over heads: coset {s, s^4, s^8, s^12} within the quarter (bits 2-3)
    d0 = fmaxf(d0, __shfl_xor(d0, 4)); d0 = fmaxf(d0, __shfl_xor(d0, 8));
    d1 = fmaxf(d1, __shfl_xor(d1, 4)); d1 = fmaxf(d1, __shfl_xor(d1, 8));
    d2 = fmaxf(d2, __shfl_xor(d2, 4)); d2 = fmaxf(d2, __shfl_xor(d2, 8));
    d3 = fmaxf(d3, __shfl_xor(d3, 4)); d3 = fmaxf(d3, __shfl_xor(d3, 8));
    d4 = fmaxf(d4, __shfl_xor(d4, 4)); d4 = fmaxf(d4, __shfl_xor(d4, 8));
    d5 = fmaxf(d5, __shfl_xor(d5, 4)); d5 = fmaxf(d5, __shfl_xor(d5, 8));
    d6 = fmaxf(d6, __shfl_xor(d6, 4)); d6 = fmaxf(d6, __shfl_xor(d6, 8));
    d7 = fmaxf(d7, __shfl_xor(d7, 4)); d7 = fmaxf(d7, __shfl_xor(d7, 8));

    if (s < 4) {
        float* op = hout + ((size_t)n << 5) + (s << 3);
        *(float4*)op = make_float4(d0, d1, d2, d3);
        *(float4*)(op + 4) = make_float4(d4, d5, d6, d7);
    }
}

// ---------------- global attention pooling ----------------
__global__ __launch_bounds__(256) void k_pool(const float* __restrict__ h2, const float* __restrict__ gW,
                                              const float* __restrict__ gb, float* __restrict__ out) {
    int b = blockIdx.x, tid = threadIdx.x;
    __shared__ float ga[NPG];
    __shared__ float red[256];
    __shared__ float gws[32];
    const float* hb = h2 + (size_t)b * NPG * 32;
    if (tid < 32) gws[tid] = gW[tid];
    __syncthreads();
    float gbv = gb[0];
    float lmax = -INFINITY;
    float gloc[4];
#pragma unroll
    for (int j = 0; j < 4; ++j) {
        int nl = tid + j * 256;
        const float* row = hb + nl * 32;
        float dot = 0.f;
#pragma unroll
        for (int c = 0; c < 32; c += 4) {
            float4 v = *(const float4*)(row + c);
            dot += v.x * gws[c] + v.y * gws[c + 1] + v.z * gws[c + 2] + v.w * gws[c + 3];
        }
        gloc[j] = dot + gbv;
        lmax = fmaxf(lmax, gloc[j]);
    }
    red[tid] = lmax; __syncthreads();
    for (int s2 = 128; s2 > 0; s2 >>= 1) { if (tid < s2) red[tid] = fmaxf(red[tid], red[tid + s2]); __syncthreads(); }
    float m = red[0];
    __syncthreads();
    float lsum = 0.f;
#pragma unroll
    for (int j = 0; j < 4; ++j) {
        int nl = tid + j * 256;
        float a = __expf(gloc[j] - m);
        ga[nl] = a;
        lsum += a;
    }
    red[tid] = lsum; __syncthreads();
    for (int s2 = 128; s2 > 0; s2 >>= 1) { if (tid < s2) red[tid] += red[tid + s2]; __syncthreads(); }
    float z = red[0];
    __syncthreads();
    int d = tid & 31, ng = tid >> 5;
    float acc = 0.f;
    for (int nl = ng; nl < NPG; nl += 8) acc += ga[nl] * hb[nl * 32 + d];
    red[tid] = acc; __syncthreads();
    if (tid < 32) {
        float s = red[tid];
#pragma unroll
        for (int g2 = 1; g2 < 8; ++g2) s += red[g2 * 32 + tid];
        out[b * 32 + tid] = s / z;
    }
}

extern "C" void kernel_launch(void* const* d_in, const int* in_sizes, int n_in,
                              void* d_out, int out_size, void* d_ws, size_t ws_size,
                              hipStream_t stream) {
    const float* x     = (const float*)d_in[0];
    const int*   src   = (const int*)d_in[1];
    const int*   dst   = (const int*)d_in[2];
    const float* Ws1   = (const float*)d_in[4];
    const float* bs1   = (const float*)d_in[5];
    const float* Wd1   = (const float*)d_in[6];
    const float* bd1   = (const float*)d_in[7];
    const float* attn1 = (const float*)d_in[8];
    const float* Ws2   = (const float*)d_in[9];
    const float* bs2   = (const float*)d_in[10];
    const float* Wd2   = (const float*)d_in[11];
    const float* bd2   = (const float*)d_in[12];
    const float* attn2 = (const float*)d_in[13];
    const float* gW    = (const float*)d_in[14];
    const float* gb    = (const float*)d_in[15];
    float* out = (float*)d_out;

    // workspace layout (~56 MB)
    u16* fsd   = (u16*)d_ws;                               // N*256 halfs (fs|fd interleaved)
    float* h1  = (float*)(fsd + (size_t)N_NODES * 256);    // N*32 f32
    float* h2  = h1 + (size_t)N_NODES * 32;                // N*32 f32
    int* rowptr = (int*)(h2 + (size_t)N_NODES * 32);       // N+1 (padded)
    int* colb   = rowptr + (N_NODES + 4);                  // E (pre-shifted byte offsets)
    __half* Wf1 = (__half*)(colb + E_TOTAL);               // 32768 halfs
    __half* Wf2 = Wf1 + 32768;                             // 8192 halfs
    int2* ndpack = (int2*)(Wf2 + 8192);                    // N int2 (sorted descriptors)

    // CSR build + degree-sort (blocks 0..63) + W fragment conversion (blocks 64..103)
    k_prep<<<B_GRAPHS + 40, 1024, 0, stream>>>(src, dst, rowptr, colb, ndpack,
                                               Ws1, Wd1, Ws2, Wd2, Wf1, Wf2);

    // layer 1
    k_gemm_mfma<128><<<N_NODES / 32, 512, 0, stream>>>(x, Wf1, bs1, bd1, fsd);
    k_edge<<<N_NODES / 16, 256, 0, stream>>>(fsd, colb, ndpack, attn1, h1);

    // layer 2 (overwrites fsd)
    k_gemm_mfma<32><<<N_NODES / 32, 512, 0, stream>>>(h1, Wf2, bs2, bd2, fsd);
    k_edge<<<N_NODES / 16, 256, 0, stream>>>(fsd, colb, ndpack, attn2, h2);

    // global attention pooling
    k_pool<<<B_GRAPHS, 256, 0, stream>>>(h2, gW, gb, out);
}